// Round 6
// baseline (138.065 us; speedup 1.0000x reference)
//
#include <hip/hip_runtime.h>
#include <hip/hip_bf16.h>
#include <hip/hip_cooperative_groups.h>

namespace cg = cooperative_groups;

typedef __attribute__((ext_vector_type(8))) short short8;
typedef __attribute__((ext_vector_type(4))) float float4v;

#define NS    64   // samples per block
#define PSTR  264  // psi/prob row stride in shorts
#define HSTR  136  // h row stride in shorts
#define ZPSTR 68   // zp row stride in floats

__device__ __forceinline__ float shflx(float v, int m) {
    return __shfl_xor(v, m, 64);
}

__device__ __forceinline__ unsigned short f2bf(float f) {
    union { __hip_bfloat16 h; unsigned short u; } cv;
    cv.h = __float2bfloat16(f);
    return cv.u;
}

__device__ __forceinline__ float bfbits(unsigned int u) {  // bf16 in high 16 bits
    union { unsigned int u; float f; } cv;
    cv.u = u;
    return cv.f;
}

// ---------------------------------------------------------------------------
// Cooperative mega kernel, grid = 256 blocks x 1024 threads (1 block/CU).
// Phase A (overlapped): wave 0 of block b simulates unitary column b ->
//   Bmat (512,256) bf16 [rows 0..255 U_re, 256..511 U_im]; wave 1 writes
//   W2T row b; ALL waves encode 64 samples -> psi (bf16 LDS).
// grid.sync()  (Bmat/W2T globally visible)
// Phase B (R4-verified): GEMM1 (MFMA 16x16x32) -> probs bf16 -> signed
//   reduce -> z -> MLP1 -> h bf16 -> GEMM2 -> out = x + b2 + D.
// MFMA maps (HW-verified): A/B row=lane&15, k=quad*8+j; C/D col=lane&15,
// row=quad*4+reg.
// ---------------------------------------------------------------------------
__global__ __launch_bounds__(1024) void vqc_mega_kernel(
    const float* __restrict__ x,
    const float* __restrict__ theta,  // (3,8)
    const float* __restrict__ phi,    // (3,8)
    const float* __restrict__ W2,     // (128,256)
    const float* __restrict__ W1,     // (8,128)
    const float* __restrict__ b1,     // (128)
    const float* __restrict__ b2,     // (256)
    unsigned short* __restrict__ Bmat,  // (512,256) bf16
    unsigned short* __restrict__ W2T,   // (256,128) bf16
    float* __restrict__ out)
{
    __shared__ __align__(16) unsigned short region[NS * PSTR];  // 33792 B
    __shared__ __align__(16) float zp_lds[NS * ZPSTR];          // 17408 B
    __shared__ float z_lds[NS][8];                              // 2048 B

    unsigned short (*psi)[PSTR]  = (unsigned short(*)[PSTR])region;
    unsigned short (*hmat)[HSTR] = (unsigned short(*)[HSTR])region;

    const int t = threadIdx.x;
    const int lane = t & 63;
    const int w = t >> 6;       // wave 0..15
    const int c = lane & 15;
    const int quad = lane >> 4;
    const int s0 = blockIdx.x * NS;

    // ================= Phase A1: wave 0 builds unitary column blockIdx ======
    if (w == 0) {
        const int j = blockIdx.x;
        float re[4], im[4];
        #pragma unroll
        for (int jj = 0; jj < 4; ++jj) {
            re[jj] = (lane * 4 + jj == j) ? 1.f : 0.f;
            im[jj] = 0.f;
        }
        for (int l = 0; l < 3; ++l) {
            #pragma unroll
            for (int q = 0; q < 6; ++q) {
                float th = 0.5f * theta[l * 8 + q];
                float ct = __cosf(th), st = __sinf(th);
                float sg = ((lane >> (5 - q)) & 1) ? st : -st;
                const int m = 1 << (5 - q);
                #pragma unroll
                for (int jj = 0; jj < 4; ++jj) {
                    float orr = shflx(re[jj], m), oi = shflx(im[jj], m);
                    re[jj] = fmaf(ct, re[jj], sg * orr);
                    im[jj] = fmaf(ct, im[jj], sg * oi);
                }
            }
            {   float th = 0.5f * theta[l * 8 + 6];
                float ct = __cosf(th), st = __sinf(th);
                #pragma unroll
                for (int jj = 0; jj < 2; ++jj) {
                    float r0 = re[jj], i0 = im[jj], r1 = re[jj + 2], i1 = im[jj + 2];
                    re[jj]     = fmaf(ct, r0, -st * r1);
                    im[jj]     = fmaf(ct, i0, -st * i1);
                    re[jj + 2] = fmaf(ct, r1,  st * r0);
                    im[jj + 2] = fmaf(ct, i1,  st * i0);
                }
            }
            {   float th = 0.5f * theta[l * 8 + 7];
                float ct = __cosf(th), st = __sinf(th);
                #pragma unroll
                for (int jj = 0; jj < 4; jj += 2) {
                    float r0 = re[jj], i0 = im[jj], r1 = re[jj + 1], i1 = im[jj + 1];
                    re[jj]     = fmaf(ct, r0, -st * r1);
                    im[jj]     = fmaf(ct, i0, -st * i1);
                    re[jj + 1] = fmaf(ct, r1,  st * r0);
                    im[jj + 1] = fmaf(ct, i1,  st * i0);
                }
            }
            #pragma unroll
            for (int q = 0; q < 5; ++q) {
                const int tm = 1 << (4 - q);
                const bool cb = (lane >> (5 - q)) & 1;
                #pragma unroll
                for (int jj = 0; jj < 4; ++jj) {
                    float orr = shflx(re[jj], tm), oi = shflx(im[jj], tm);
                    re[jj] = cb ? orr : re[jj];
                    im[jj] = cb ? oi  : im[jj];
                }
            }
            {   const bool cb = lane & 1;
                float tt;
                tt = re[0]; re[0] = cb ? re[2] : re[0]; re[2] = cb ? tt : re[2];
                tt = im[0]; im[0] = cb ? im[2] : im[0]; im[2] = cb ? tt : im[2];
                tt = re[1]; re[1] = cb ? re[3] : re[1]; re[3] = cb ? tt : re[3];
                tt = im[1]; im[1] = cb ? im[3] : im[1]; im[3] = cb ? tt : im[3];
            }
            {   float tt;
                tt = re[2]; re[2] = re[3]; re[3] = tt;
                tt = im[2]; im[2] = im[3]; im[3] = tt;
            }
            {   re[1] = shflx(re[1], 32); im[1] = shflx(im[1], 32);
                re[3] = shflx(re[3], 32); im[3] = shflx(im[3], 32);
            }
            float al = 0.f;
            #pragma unroll
            for (int q = 0; q < 6; ++q) {
                float h = 0.5f * phi[l * 8 + q];
                al += ((lane >> (5 - q)) & 1) ? h : -h;
            }
            float h6 = 0.5f * phi[l * 8 + 6], h7 = 0.5f * phi[l * 8 + 7];
            float ajs[4] = { al - h6 - h7, al - h6 + h7, al + h6 - h7, al + h6 + h7 };
            #pragma unroll
            for (int jj = 0; jj < 4; ++jj) {
                float cc = __cosf(ajs[jj]), sn = __sinf(ajs[jj]);
                float r = re[jj], i = im[jj];
                re[jj] = r * cc - i * sn;
                im[jj] = fmaf(r, sn, i * cc);
            }
        }
        #pragma unroll
        for (int jj = 0; jj < 4; ++jj) {
            int kp = lane * 4 + jj;
            Bmat[(size_t)kp * 256 + j]         = f2bf(re[jj]);
            Bmat[(size_t)(kp + 256) * 256 + j] = f2bf(im[jj]);
        }
    } else if (w == 1) {
        // ---- Phase A2: W2T row blockIdx ----
        const int n = blockIdx.x;
        float a0 = W2[(2 * lane)     * 256 + n];
        float a1 = W2[(2 * lane + 1) * 256 + n];
        ushort2 pk;
        pk.x = f2bf(a0);
        pk.y = f2bf(a1);
        *reinterpret_cast<ushort2*>(W2T + n * 128 + 2 * lane) = pk;
    }

    // ================= Phase A3: encode (all threads) =======================
    {
        const int g = t >> 4;     // local sample 0..63
        const int sub = t & 15;
        const float4* xr = reinterpret_cast<const float4*>(x + (size_t)(s0 + g) * 256) + sub * 4;
        float4 v0 = xr[0], v1 = xr[1], v2 = xr[2], v3 = xr[3];
        float mn = fminf(fminf(fminf(v0.x, v0.y), fminf(v0.z, v0.w)),
                         fminf(fminf(v1.x, v1.y), fminf(v1.z, v1.w)));
        mn = fminf(mn, fminf(fminf(fminf(v2.x, v2.y), fminf(v2.z, v2.w)),
                             fminf(fminf(v3.x, v3.y), fminf(v3.z, v3.w))));
        float mx = fmaxf(fmaxf(fmaxf(v0.x, v0.y), fmaxf(v0.z, v0.w)),
                         fmaxf(fmaxf(v1.x, v1.y), fmaxf(v1.z, v1.w)));
        mx = fmaxf(mx, fmaxf(fmaxf(fmaxf(v2.x, v2.y), fmaxf(v2.z, v2.w)),
                             fmaxf(fmaxf(v3.x, v3.y), fmaxf(v3.z, v3.w))));
        #pragma unroll
        for (int m = 1; m < 16; m <<= 1) {
            mn = fminf(mn, shflx(mn, m));
            mx = fmaxf(mx, shflx(mx, m));
        }
        const float scale = 0.78539816339744831f / (mx - mn + 1e-8f);  // half-angle

        const int base = lane & 48;
        float xq[8];
        xq[0] = __shfl(v0.x, base); xq[1] = __shfl(v0.y, base);
        xq[2] = __shfl(v0.z, base); xq[3] = __shfl(v0.w, base);
        xq[4] = __shfl(v1.x, base); xq[5] = __shfl(v1.y, base);
        xq[6] = __shfl(v1.z, base); xq[7] = __shfl(v1.w, base);

        float cq[8], sq[8];
        #pragma unroll
        for (int q = 0; q < 8; ++q) {
            float a = (xq[q] - mn) * scale;
            cq[q] = __cosf(a);
            sq[q] = __sinf(a);
        }
        // amp idx = sub*16 + nl; qubit q <-> idx bit (7-q); sub = bits 7..4
        float pref = ((sub & 8) ? sq[0] : cq[0]) *
                     ((sub & 4) ? sq[1] : cq[1]) *
                     ((sub & 2) ? sq[2] : cq[2]) *
                     ((sub & 1) ? sq[3] : cq[3]);
        float p1[2], p2[4], p3[8];
        p1[0] = pref * cq[4]; p1[1] = pref * sq[4];
        #pragma unroll
        for (int i = 0; i < 2; ++i) { p2[2*i] = p1[i] * cq[5]; p2[2*i+1] = p1[i] * sq[5]; }
        #pragma unroll
        for (int i = 0; i < 4; ++i) { p3[2*i] = p2[i] * cq[6]; p3[2*i+1] = p2[i] * sq[6]; }
        #pragma unroll
        for (int i = 0; i < 4; ++i) {
            ushort4 pk;
            pk.x = f2bf(p3[2*i]     * cq[7]);
            pk.y = f2bf(p3[2*i]     * sq[7]);
            pk.z = f2bf(p3[2*i + 1] * cq[7]);
            pk.w = f2bf(p3[2*i + 1] * sq[7]);
            *reinterpret_cast<ushort4*>(&psi[g][sub * 16 + 4 * i]) = pk;
        }
    }

    cg::this_grid().sync();  // Bmat/W2T visible device-wide; psi visible in-block

    // ================= Phase B: GEMM1 =======================================
    float4v accre[4], accim[4];
    #pragma unroll
    for (int mt = 0; mt < 4; ++mt) {
        accre[mt] = (float4v){0.f, 0.f, 0.f, 0.f};
        accim[mt] = (float4v){0.f, 0.f, 0.f, 0.f};
    }
    #pragma unroll
    for (int kk = 0; kk < 8; ++kk) {
        const int ko = kk * 32 + quad * 8;
        short8 a0 = *(const short8*)(&psi[c][ko]);
        short8 a1 = *(const short8*)(&psi[16 + c][ko]);
        short8 a2 = *(const short8*)(&psi[32 + c][ko]);
        short8 a3 = *(const short8*)(&psi[48 + c][ko]);
        short8 bre = *(const short8*)(Bmat + (size_t)(w * 16 + c) * 256 + ko);
        short8 bim = *(const short8*)(Bmat + (size_t)(256 + w * 16 + c) * 256 + ko);
        accre[0] = __builtin_amdgcn_mfma_f32_16x16x32_bf16(a0, bre, accre[0], 0, 0, 0);
        accre[1] = __builtin_amdgcn_mfma_f32_16x16x32_bf16(a1, bre, accre[1], 0, 0, 0);
        accre[2] = __builtin_amdgcn_mfma_f32_16x16x32_bf16(a2, bre, accre[2], 0, 0, 0);
        accre[3] = __builtin_amdgcn_mfma_f32_16x16x32_bf16(a3, bre, accre[3], 0, 0, 0);
        accim[0] = __builtin_amdgcn_mfma_f32_16x16x32_bf16(a0, bim, accim[0], 0, 0, 0);
        accim[1] = __builtin_amdgcn_mfma_f32_16x16x32_bf16(a1, bim, accim[1], 0, 0, 0);
        accim[2] = __builtin_amdgcn_mfma_f32_16x16x32_bf16(a2, bim, accim[2], 0, 0, 0);
        accim[3] = __builtin_amdgcn_mfma_f32_16x16x32_bf16(a3, bim, accim[3], 0, 0, 0);
    }
    __syncthreads();  // psi reads done before probs overwrite region

    // ---- probs (bf16) into region ----
    #pragma unroll
    for (int mt = 0; mt < 4; ++mt)
        #pragma unroll
        for (int r = 0; r < 4; ++r) {
            const int m = mt * 16 + quad * 4 + r;
            const float pr = accre[mt][r], pi = accim[mt][r];
            psi[m][w * 16 + c] = f2bf(pr * pr + pi * pi);
        }
    __syncthreads();

    // ---- chunked signed reduce: thread (m, h) covers cols h*32..h*32+31 ----
    if (t < 512) {
        const int m = t >> 3, h = t & 7;
        const uint4* pu = (const uint4*)(&psi[m][h * 32]);
        float s[8], d6s = 0.f, d7s = 0.f;
        #pragma unroll
        for (int i = 0; i < 4; ++i) {
            uint4 u = pu[i];
            {   float e0 = bfbits(u.x << 16), e1 = bfbits(u.x & 0xffff0000u);
                float e2 = bfbits(u.y << 16), e3 = bfbits(u.y & 0xffff0000u);
                float a01 = e0 + e1, a23 = e2 + e3;
                s[2*i] = a01 + a23;
                d6s += a01 - a23;
                d7s += (e0 - e1) + (e2 - e3);
            }
            {   float e0 = bfbits(u.z << 16), e1 = bfbits(u.z & 0xffff0000u);
                float e2 = bfbits(u.w << 16), e3 = bfbits(u.w & 0xffff0000u);
                float a01 = e0 + e1, a23 = e2 + e3;
                s[2*i+1] = a01 + a23;
                d6s += a01 - a23;
                d7s += (e0 - e1) + (e2 - e3);
            }
        }
        float t01 = s[0] + s[1], t23 = s[2] + s[3], t45 = s[4] + s[5], t67 = s[6] + s[7];
        float u03 = t01 + t23, u47 = t45 + t67;
        float S  = u03 + u47;
        float S3 = u03 - u47;                  // n bit4
        float S4 = (t01 - t23) + (t45 - t67);  // n bit3
        float S5 = (s[0]-s[1]) + (s[2]-s[3]) + (s[4]-s[5]) + (s[6]-s[7]);  // n bit2
        float* zr = &zp_lds[m * ZPSTR + h * 8];
        zr[0] = (h & 4) ? -S : S;   // q0 <- n bit7 = h bit2
        zr[1] = (h & 2) ? -S : S;   // q1 <- n bit6
        zr[2] = (h & 1) ? -S : S;   // q2 <- n bit5
        zr[3] = S3; zr[4] = S4; zr[5] = S5; zr[6] = d6s; zr[7] = d7s;
    }
    __syncthreads();

    if (t < 512) {
        const int m = t >> 3, q = t & 7;
        float zv = 0.f;
        #pragma unroll
        for (int h = 0; h < 8; ++h) zv += zp_lds[m * ZPSTR + h * 8 + q];
        z_lds[m][q] = zv;
    }
    __syncthreads();

    // ---- MLP1: h = relu(z@W1 + b1) -> bf16 (aliases region) ----
    {
        const int j = t & 127, ig = t >> 7;
        float w1v[8];
        #pragma unroll
        for (int q = 0; q < 8; ++q) w1v[q] = W1[q * 128 + j];
        const float b1v = b1[j];
        #pragma unroll
        for (int ii = 0; ii < 8; ++ii) {
            const int i = ig * 8 + ii;
            float a = b1v;
            #pragma unroll
            for (int q = 0; q < 8; ++q) a = fmaf(z_lds[i][q], w1v[q], a);
            hmat[i][j] = f2bf(fmaxf(a, 0.f));
        }
    }
    __syncthreads();

    // ---- GEMM2: wave w -> cols n = w*16+c of h @ W2 ----
    float4v acc2[4];
    #pragma unroll
    for (int mt = 0; mt < 4; ++mt) acc2[mt] = (float4v){0.f, 0.f, 0.f, 0.f};
    #pragma unroll
    for (int kk = 0; kk < 4; ++kk) {
        const int ko = kk * 32 + quad * 8;
        short8 a0 = *(const short8*)(&hmat[c][ko]);
        short8 a1 = *(const short8*)(&hmat[16 + c][ko]);
        short8 a2 = *(const short8*)(&hmat[32 + c][ko]);
        short8 a3 = *(const short8*)(&hmat[48 + c][ko]);
        short8 bw = *(const short8*)(W2T + (size_t)(w * 16 + c) * 128 + ko);
        acc2[0] = __builtin_amdgcn_mfma_f32_16x16x32_bf16(a0, bw, acc2[0], 0, 0, 0);
        acc2[1] = __builtin_amdgcn_mfma_f32_16x16x32_bf16(a1, bw, acc2[1], 0, 0, 0);
        acc2[2] = __builtin_amdgcn_mfma_f32_16x16x32_bf16(a2, bw, acc2[2], 0, 0, 0);
        acc2[3] = __builtin_amdgcn_mfma_f32_16x16x32_bf16(a3, bw, acc2[3], 0, 0, 0);
    }

    // ---- epilogue: out = x + b2 + D (x slab L2-hot from encode) ----
    {
        const int n = w * 16 + c;
        const float b2v = b2[n];
        #pragma unroll
        for (int mt = 0; mt < 4; ++mt)
            #pragma unroll
            for (int r = 0; r < 4; ++r) {
                const int m = mt * 16 + quad * 4 + r;
                const size_t idx = (size_t)(s0 + m) * 256 + n;
                out[idx] = x[idx] + b2v + acc2[mt][r];
            }
    }
}

extern "C" void kernel_launch(void* const* d_in, const int* in_sizes, int n_in,
                              void* d_out, int out_size, void* d_ws, size_t ws_size,
                              hipStream_t stream) {
    const float* x     = (const float*)d_in[0];
    const float* theta = (const float*)d_in[1];
    const float* phi   = (const float*)d_in[2];
    const float* W1    = (const float*)d_in[3];
    const float* b1    = (const float*)d_in[4];
    const float* W2    = (const float*)d_in[5];
    const float* b2    = (const float*)d_in[6];
    float* out = (float*)d_out;
    const int B = in_sizes[0] / 256;

    unsigned short* Bmat = (unsigned short*)d_ws;   // (512,256) bf16
    unsigned short* W2T  = Bmat + 512 * 256;        // (256,128) bf16

    void* args[] = { (void*)&x, (void*)&theta, (void*)&phi, (void*)&W2,
                     (void*)&W1, (void*)&b1, (void*)&b2,
                     (void*)&Bmat, (void*)&W2T, (void*)&out };
    hipLaunchCooperativeKernel((void*)vqc_mega_kernel, dim3(B / NS), dim3(1024),
                               args, 0, stream);
}

// Round 7
// 99.405 us; speedup vs baseline: 1.3889x; 1.3889x over previous
//
#include <hip/hip_runtime.h>
#include <hip/hip_bf16.h>

typedef __attribute__((ext_vector_type(8))) short short8;
typedef __attribute__((ext_vector_type(4))) float float4v;

#define NS    64   // samples per mega block
#define PSTR  264  // psi/p row stride in shorts (132 dwords = +4 banks/row)
#define HSTR  136  // h row stride in shorts
#define ZPSTR 68   // zp row stride in floats

__device__ __forceinline__ float shflx(float v, int m) {
    return __shfl_xor(v, m, 64);
}

__device__ __forceinline__ unsigned short f2bf(float f) {
    union { __hip_bfloat16 h; unsigned short u; } cv;
    cv.h = __float2bfloat16(f);
    return cv.u;
}

__device__ __forceinline__ float bfbits(unsigned int u) {  // bf16 in high 16 bits
    union { unsigned int u; float f; } cv;
    cv.u = u;
    return cv.f;
}

// ---------------------------------------------------------------------------
// K1: 64 blocks. Each block: 4 waves simulate unitary columns 4b..4b+3
// (verified rounds 1-5) -> Bmat (512,256) bf16 [rows 0..255 U_re[n][k],
// 256..511 U_im[n][k]]; then all 256 threads transpose 2 k-rows of W2 ->
// W2T (256,128) bf16.
// ---------------------------------------------------------------------------
__global__ __launch_bounds__(256) void vqc_build_u_kernel(
    const float* __restrict__ theta,
    const float* __restrict__ phi,
    const float* __restrict__ W2,
    unsigned short* __restrict__ Bmat,
    unsigned short* __restrict__ W2T)
{
    const int b = blockIdx.x;
    const int lane = threadIdx.x & 63;
    const int j = (b << 2) + (threadIdx.x >> 6);

    float re[4], im[4];
    #pragma unroll
    for (int jj = 0; jj < 4; ++jj) {
        re[jj] = (lane * 4 + jj == j) ? 1.f : 0.f;
        im[jj] = 0.f;
    }

    for (int l = 0; l < 3; ++l) {
        #pragma unroll
        for (int q = 0; q < 6; ++q) {
            float th = 0.5f * theta[l * 8 + q];
            float ct = __cosf(th), st = __sinf(th);
            float sg = ((lane >> (5 - q)) & 1) ? st : -st;
            const int m = 1 << (5 - q);
            #pragma unroll
            for (int jj = 0; jj < 4; ++jj) {
                float orr = shflx(re[jj], m), oi = shflx(im[jj], m);
                re[jj] = fmaf(ct, re[jj], sg * orr);
                im[jj] = fmaf(ct, im[jj], sg * oi);
            }
        }
        {   float th = 0.5f * theta[l * 8 + 6];
            float ct = __cosf(th), st = __sinf(th);
            #pragma unroll
            for (int jj = 0; jj < 2; ++jj) {
                float r0 = re[jj], i0 = im[jj], r1 = re[jj + 2], i1 = im[jj + 2];
                re[jj]     = fmaf(ct, r0, -st * r1);
                im[jj]     = fmaf(ct, i0, -st * i1);
                re[jj + 2] = fmaf(ct, r1,  st * r0);
                im[jj + 2] = fmaf(ct, i1,  st * i0);
            }
        }
        {   float th = 0.5f * theta[l * 8 + 7];
            float ct = __cosf(th), st = __sinf(th);
            #pragma unroll
            for (int jj = 0; jj < 4; jj += 2) {
                float r0 = re[jj], i0 = im[jj], r1 = re[jj + 1], i1 = im[jj + 1];
                re[jj]     = fmaf(ct, r0, -st * r1);
                im[jj]     = fmaf(ct, i0, -st * i1);
                re[jj + 1] = fmaf(ct, r1,  st * r0);
                im[jj + 1] = fmaf(ct, i1,  st * i0);
            }
        }
        #pragma unroll
        for (int q = 0; q < 5; ++q) {
            const int tm = 1 << (4 - q);
            const bool cb = (lane >> (5 - q)) & 1;
            #pragma unroll
            for (int jj = 0; jj < 4; ++jj) {
                float orr = shflx(re[jj], tm), oi = shflx(im[jj], tm);
                re[jj] = cb ? orr : re[jj];
                im[jj] = cb ? oi  : im[jj];
            }
        }
        {   const bool cb = lane & 1;
            float t;
            t = re[0]; re[0] = cb ? re[2] : re[0]; re[2] = cb ? t : re[2];
            t = im[0]; im[0] = cb ? im[2] : im[0]; im[2] = cb ? t : im[2];
            t = re[1]; re[1] = cb ? re[3] : re[1]; re[3] = cb ? t : re[3];
            t = im[1]; im[1] = cb ? im[3] : im[1]; im[3] = cb ? t : im[3];
        }
        {   float t;
            t = re[2]; re[2] = re[3]; re[3] = t;
            t = im[2]; im[2] = im[3]; im[3] = t;
        }
        {   re[1] = shflx(re[1], 32); im[1] = shflx(im[1], 32);
            re[3] = shflx(re[3], 32); im[3] = shflx(im[3], 32);
        }
        float al = 0.f;
        #pragma unroll
        for (int q = 0; q < 6; ++q) {
            float h = 0.5f * phi[l * 8 + q];
            al += ((lane >> (5 - q)) & 1) ? h : -h;
        }
        float h6 = 0.5f * phi[l * 8 + 6], h7 = 0.5f * phi[l * 8 + 7];
        float ajs[4] = { al - h6 - h7, al - h6 + h7, al + h6 - h7, al + h6 + h7 };
        #pragma unroll
        for (int jj = 0; jj < 4; ++jj) {
            float cc = __cosf(ajs[jj]), sn = __sinf(ajs[jj]);
            float r = re[jj], i = im[jj];
            re[jj] = r * cc - i * sn;
            im[jj] = fmaf(r, sn, i * cc);
        }
    }

    #pragma unroll
    for (int jj = 0; jj < 4; ++jj) {
        int kp = lane * 4 + jj;
        Bmat[(size_t)kp * 256 + j]         = f2bf(re[jj]);
        Bmat[(size_t)(kp + 256) * 256 + j] = f2bf(im[jj]);
    }

    // ---- W2T: this block transposes k-rows 2b, 2b+1 (coalesced reads) ----
    {
        const int k0 = b * 2;
        const int n = threadIdx.x;
        ushort2 pk;
        pk.x = f2bf(W2[(k0 + 0) * 256 + n]);
        pk.y = f2bf(W2[(k0 + 1) * 256 + n]);
        *reinterpret_cast<ushort2*>(W2T + n * 128 + k0) = pk;
    }
}

// ---------------------------------------------------------------------------
// K2: mega-fused (R4-verified fastest config), 64 samples / 1024 threads
// (16 waves) / block, grid = B/64 = 256 (1 block/CU).
// encode -> psi(bf16,LDS) -> GEMM1 (MFMA; wave w owns cols w*16..+15, re+im)
// -> probs bf16 (alias psi) -> chunked signed reduce -> z -> MLP1 -> h bf16
// (alias) -> GEMM2 MFMA -> out = x + b2 + D.
// MFMA maps (HW-verified): A/B row=lane&15, k=quad*8+j; C/D col=lane&15,
// row=quad*4+reg.
// ---------------------------------------------------------------------------
__global__ __launch_bounds__(1024) void vqc_mega_kernel(
    const float* __restrict__ x,
    const unsigned short* __restrict__ Bmat,  // (512,256) bf16
    const unsigned short* __restrict__ W2T,   // (256,128) bf16
    const float* __restrict__ W1,             // (8,128)
    const float* __restrict__ b1,             // (128)
    const float* __restrict__ b2,             // (256)
    float* __restrict__ out)
{
    __shared__ __align__(16) unsigned short region[NS * PSTR];  // 33792 B
    __shared__ __align__(16) float zp_lds[NS * ZPSTR];          // 17408 B
    __shared__ float z_lds[NS][8];                              // 2048 B

    unsigned short (*psi)[PSTR]  = (unsigned short(*)[PSTR])region;
    unsigned short (*hmat)[HSTR] = (unsigned short(*)[HSTR])region;

    const int t = threadIdx.x;
    const int lane = t & 63;
    const int w = t >> 6;       // wave 0..15
    const int c = lane & 15;
    const int quad = lane >> 4;
    const int s0 = blockIdx.x * NS;

    // ---- encode: 16 threads / sample, thread owns amps sub*16..sub*16+15 ----
    {
        const int g = t >> 4;     // local sample 0..63
        const int sub = t & 15;
        const float4* xr = reinterpret_cast<const float4*>(x + (size_t)(s0 + g) * 256) + sub * 4;
        float4 v0 = xr[0], v1 = xr[1], v2 = xr[2], v3 = xr[3];
        float mn = fminf(fminf(fminf(v0.x, v0.y), fminf(v0.z, v0.w)),
                         fminf(fminf(v1.x, v1.y), fminf(v1.z, v1.w)));
        mn = fminf(mn, fminf(fminf(fminf(v2.x, v2.y), fminf(v2.z, v2.w)),
                             fminf(fminf(v3.x, v3.y), fminf(v3.z, v3.w))));
        float mx = fmaxf(fmaxf(fmaxf(v0.x, v0.y), fmaxf(v0.z, v0.w)),
                         fmaxf(fmaxf(v1.x, v1.y), fmaxf(v1.z, v1.w)));
        mx = fmaxf(mx, fmaxf(fmaxf(fmaxf(v2.x, v2.y), fmaxf(v2.z, v2.w)),
                             fmaxf(fmaxf(v3.x, v3.y), fmaxf(v3.z, v3.w))));
        #pragma unroll
        for (int m = 1; m < 16; m <<= 1) {
            mn = fminf(mn, shflx(mn, m));
            mx = fmaxf(mx, shflx(mx, m));
        }
        const float scale = 0.78539816339744831f / (mx - mn + 1e-8f);  // half-angle

        const int base = lane & 48;  // sub==0 lane of the 16-lane group
        float xq[8];
        xq[0] = __shfl(v0.x, base); xq[1] = __shfl(v0.y, base);
        xq[2] = __shfl(v0.z, base); xq[3] = __shfl(v0.w, base);
        xq[4] = __shfl(v1.x, base); xq[5] = __shfl(v1.y, base);
        xq[6] = __shfl(v1.z, base); xq[7] = __shfl(v1.w, base);

        float cq[8], sq[8];
        #pragma unroll
        for (int q = 0; q < 8; ++q) {
            float a = (xq[q] - mn) * scale;
            cq[q] = __cosf(a);
            sq[q] = __sinf(a);
        }
        // amp idx = sub*16 + nl; qubit q <-> idx bit (7-q); sub = bits 7..4
        float pref = ((sub & 8) ? sq[0] : cq[0]) *
                     ((sub & 4) ? sq[1] : cq[1]) *
                     ((sub & 2) ? sq[2] : cq[2]) *
                     ((sub & 1) ? sq[3] : cq[3]);
        float p1[2], p2[4], p3[8];
        p1[0] = pref * cq[4]; p1[1] = pref * sq[4];
        #pragma unroll
        for (int i = 0; i < 2; ++i) { p2[2*i] = p1[i] * cq[5]; p2[2*i+1] = p1[i] * sq[5]; }
        #pragma unroll
        for (int i = 0; i < 4; ++i) { p3[2*i] = p2[i] * cq[6]; p3[2*i+1] = p2[i] * sq[6]; }
        #pragma unroll
        for (int i = 0; i < 4; ++i) {
            ushort4 pk;
            pk.x = f2bf(p3[2*i]     * cq[7]);
            pk.y = f2bf(p3[2*i]     * sq[7]);
            pk.z = f2bf(p3[2*i + 1] * cq[7]);
            pk.w = f2bf(p3[2*i + 1] * sq[7]);
            *reinterpret_cast<ushort4*>(&psi[g][sub * 16 + 4 * i]) = pk;
        }
    }
    __syncthreads();

    // ---- GEMM1: wave w -> cols n = w*16+c of Phi_re and Phi_im ----
    float4v accre[4], accim[4];
    #pragma unroll
    for (int mt = 0; mt < 4; ++mt) {
        accre[mt] = (float4v){0.f, 0.f, 0.f, 0.f};
        accim[mt] = (float4v){0.f, 0.f, 0.f, 0.f};
    }
    #pragma unroll
    for (int kk = 0; kk < 8; ++kk) {
        const int ko = kk * 32 + quad * 8;
        short8 a0 = *(const short8*)(&psi[c][ko]);
        short8 a1 = *(const short8*)(&psi[16 + c][ko]);
        short8 a2 = *(const short8*)(&psi[32 + c][ko]);
        short8 a3 = *(const short8*)(&psi[48 + c][ko]);
        short8 bre = *(const short8*)(Bmat + (size_t)(w * 16 + c) * 256 + ko);
        short8 bim = *(const short8*)(Bmat + (size_t)(256 + w * 16 + c) * 256 + ko);
        accre[0] = __builtin_amdgcn_mfma_f32_16x16x32_bf16(a0, bre, accre[0], 0, 0, 0);
        accre[1] = __builtin_amdgcn_mfma_f32_16x16x32_bf16(a1, bre, accre[1], 0, 0, 0);
        accre[2] = __builtin_amdgcn_mfma_f32_16x16x32_bf16(a2, bre, accre[2], 0, 0, 0);
        accre[3] = __builtin_amdgcn_mfma_f32_16x16x32_bf16(a3, bre, accre[3], 0, 0, 0);
        accim[0] = __builtin_amdgcn_mfma_f32_16x16x32_bf16(a0, bim, accim[0], 0, 0, 0);
        accim[1] = __builtin_amdgcn_mfma_f32_16x16x32_bf16(a1, bim, accim[1], 0, 0, 0);
        accim[2] = __builtin_amdgcn_mfma_f32_16x16x32_bf16(a2, bim, accim[2], 0, 0, 0);
        accim[3] = __builtin_amdgcn_mfma_f32_16x16x32_bf16(a3, bim, accim[3], 0, 0, 0);
    }
    __syncthreads();  // psi reads done before p overwrites region

    // ---- probs (bf16) into region ----
    #pragma unroll
    for (int mt = 0; mt < 4; ++mt)
        #pragma unroll
        for (int r = 0; r < 4; ++r) {
            const int m = mt * 16 + quad * 4 + r;
            const float pr = accre[mt][r], pi = accim[mt][r];
            psi[m][w * 16 + c] = f2bf(pr * pr + pi * pi);
        }
    __syncthreads();

    // ---- chunked signed reduce: thread (m, h) covers cols h*32..h*32+31 ----
    if (t < 512) {
        const int m = t >> 3, h = t & 7;
        const uint4* pu = (const uint4*)(&psi[m][h * 32]);
        float s[8], d6s = 0.f, d7s = 0.f;
        #pragma unroll
        for (int i = 0; i < 4; ++i) {
            uint4 u = pu[i];
            {   float e0 = bfbits(u.x << 16), e1 = bfbits(u.x & 0xffff0000u);
                float e2 = bfbits(u.y << 16), e3 = bfbits(u.y & 0xffff0000u);
                float a01 = e0 + e1, a23 = e2 + e3;
                s[2*i] = a01 + a23;
                d6s += a01 - a23;
                d7s += (e0 - e1) + (e2 - e3);
            }
            {   float e0 = bfbits(u.z << 16), e1 = bfbits(u.z & 0xffff0000u);
                float e2 = bfbits(u.w << 16), e3 = bfbits(u.w & 0xffff0000u);
                float a01 = e0 + e1, a23 = e2 + e3;
                s[2*i+1] = a01 + a23;
                d6s += a01 - a23;
                d7s += (e0 - e1) + (e2 - e3);
            }
        }
        float t01 = s[0] + s[1], t23 = s[2] + s[3], t45 = s[4] + s[5], t67 = s[6] + s[7];
        float u03 = t01 + t23, u47 = t45 + t67;
        float S  = u03 + u47;
        float S3 = u03 - u47;                  // n bit4
        float S4 = (t01 - t23) + (t45 - t67);  // n bit3
        float S5 = (s[0]-s[1]) + (s[2]-s[3]) + (s[4]-s[5]) + (s[6]-s[7]);  // n bit2
        float* zr = &zp_lds[m * ZPSTR + h * 8];
        zr[0] = (h & 4) ? -S : S;   // q0 <- n bit7 = h bit2
        zr[1] = (h & 2) ? -S : S;   // q1 <- n bit6
        zr[2] = (h & 1) ? -S : S;   // q2 <- n bit5
        zr[3] = S3; zr[4] = S4; zr[5] = S5; zr[6] = d6s; zr[7] = d7s;
    }
    __syncthreads();

    if (t < 512) {
        const int m = t >> 3, q = t & 7;
        float zv = 0.f;
        #pragma unroll
        for (int h = 0; h < 8; ++h) zv += zp_lds[m * ZPSTR + h * 8 + q];
        z_lds[m][q] = zv;
    }
    __syncthreads();

    // ---- MLP1: h = relu(z@W1 + b1) -> bf16 (alias region) ----
    {
        const int j = t & 127, ig = t >> 7;
        float w1v[8];
        #pragma unroll
        for (int q = 0; q < 8; ++q) w1v[q] = W1[q * 128 + j];
        const float b1v = b1[j];
        #pragma unroll
        for (int ii = 0; ii < 8; ++ii) {
            const int i = ig * 8 + ii;
            float a = b1v;
            #pragma unroll
            for (int q = 0; q < 8; ++q) a = fmaf(z_lds[i][q], w1v[q], a);
            hmat[i][j] = f2bf(fmaxf(a, 0.f));
        }
    }
    __syncthreads();

    // ---- GEMM2: wave w -> cols n = w*16+c of h @ W2 ----
    float4v acc2[4];
    #pragma unroll
    for (int mt = 0; mt < 4; ++mt) acc2[mt] = (float4v){0.f, 0.f, 0.f, 0.f};
    #pragma unroll
    for (int kk = 0; kk < 4; ++kk) {
        const int ko = kk * 32 + quad * 8;
        short8 a0 = *(const short8*)(&hmat[c][ko]);
        short8 a1 = *(const short8*)(&hmat[16 + c][ko]);
        short8 a2 = *(const short8*)(&hmat[32 + c][ko]);
        short8 a3 = *(const short8*)(&hmat[48 + c][ko]);
        short8 bw = *(const short8*)(W2T + (size_t)(w * 16 + c) * 128 + ko);
        acc2[0] = __builtin_amdgcn_mfma_f32_16x16x32_bf16(a0, bw, acc2[0], 0, 0, 0);
        acc2[1] = __builtin_amdgcn_mfma_f32_16x16x32_bf16(a1, bw, acc2[1], 0, 0, 0);
        acc2[2] = __builtin_amdgcn_mfma_f32_16x16x32_bf16(a2, bw, acc2[2], 0, 0, 0);
        acc2[3] = __builtin_amdgcn_mfma_f32_16x16x32_bf16(a3, bw, acc2[3], 0, 0, 0);
    }

    // ---- epilogue: out = x + b2 + D (x slab L2-hot from encode) ----
    {
        const int n = w * 16 + c;
        const float b2v = b2[n];
        #pragma unroll
        for (int mt = 0; mt < 4; ++mt)
            #pragma unroll
            for (int r = 0; r < 4; ++r) {
                const int m = mt * 16 + quad * 4 + r;
                const size_t idx = (size_t)(s0 + m) * 256 + n;
                out[idx] = x[idx] + b2v + acc2[mt][r];
            }
    }
}

extern "C" void kernel_launch(void* const* d_in, const int* in_sizes, int n_in,
                              void* d_out, int out_size, void* d_ws, size_t ws_size,
                              hipStream_t stream) {
    const float* x     = (const float*)d_in[0];
    const float* theta = (const float*)d_in[1];
    const float* phi   = (const float*)d_in[2];
    const float* W1    = (const float*)d_in[3];
    const float* b1    = (const float*)d_in[4];
    const float* W2    = (const float*)d_in[5];
    const float* b2    = (const float*)d_in[6];
    float* out = (float*)d_out;
    const int B = in_sizes[0] / 256;

    unsigned short* Bmat = (unsigned short*)d_ws;   // (512,256) bf16
    unsigned short* W2T  = Bmat + 512 * 256;        // (256,128) bf16

    vqc_build_u_kernel<<<dim3(64), dim3(256), 0, stream>>>(theta, phi, W2, Bmat, W2T);
    vqc_mega_kernel<<<dim3(B / NS), dim3(1024), 0, stream>>>(
        x, Bmat, W2T, W1, b1, b2, out);
}